// Round 4
// baseline (1389.882 us; speedup 1.0000x reference)
//
#include <hip/hip_runtime.h>
#include <cstdint>
#include <cstddef>

// Problem constants: B=4,S=1024 -> T=4096 tokens
#define T_TOK 4096
#define DDIM 1024
#define HDIM 4096
#define NEXP 8
#define NSHARED 2
#define RT_CAP 9216   // max compact routing rows (8192 + 8*128 align slack)

typedef unsigned short ushort_t;
typedef __attribute__((ext_vector_type(8))) short short8;   // 8 bf16 (MFMA A/B frag)
typedef __attribute__((ext_vector_type(4))) float f32x4;    // MFMA C/D frag

__device__ inline ushort_t f2bf(float f) {
  unsigned u = __float_as_uint(f);
  u += 0x7fffu + ((u >> 16) & 1u);
  return (ushort_t)(u >> 16);
}

// async global->LDS 16B/lane. LDS dest must be wave-uniform base + lane*16;
// global source may be per-lane arbitrary (gather is legal).
__device__ inline void async_copy16(const ushort_t* g, ushort_t* l) {
  __builtin_amdgcn_global_load_lds(
      (const __attribute__((address_space(1))) void*)g,
      (__attribute__((address_space(3))) void*)l, 16, 0, 0);
}

// JAX tanh-gelu as x*sigmoid(2u) — algebraically identical, ~7 VALU ops.
__device__ inline float gelu_tanh(float x) {
  float x2 = x * x;
  float t = fmaf(0.07135481627133721f, x2, 1.5957691216057308f);  // 2u = x*t
  float e = __expf(-x * t);                                       // exp(-2u)
  return x * __builtin_amdgcn_rcpf(1.0f + e);
}

// Pipeline boundary: counted vmcnt across a raw barrier — newest STAGE's 4
// loads stay in flight; older stage (next tile's data) guaranteed landed.
#define PIPE_BOUNDARY()                                     \
  __builtin_amdgcn_sched_barrier(0);                        \
  asm volatile("s_waitcnt vmcnt(4)" ::: "memory");          \
  __builtin_amdgcn_s_barrier();                             \
  asm volatile("" ::: "memory");                            \
  __builtin_amdgcn_sched_barrier(0);

// ---------------- router: top-2 of (x@Wr + br + gumbel); count per expert ---
__global__ __launch_bounds__(256) void router_kernel(
    const float* __restrict__ x, const float* __restrict__ Wr,
    const float* __restrict__ br, const float* __restrict__ gum,
    int* __restrict__ choice, int* __restrict__ cnt) {
  int lane = threadIdx.x & 63;
  int wv = blockIdx.x * 4 + (threadIdx.x >> 6);
  if (wv >= T_TOK) return;
  const float* xr = x + (long)wv * DDIM;
  float acc[NEXP] = {0.f, 0.f, 0.f, 0.f, 0.f, 0.f, 0.f, 0.f};
  for (int d = lane; d < DDIM; d += 64) {
    float xv = xr[d];
    const float* w = Wr + d * NEXP;
#pragma unroll
    for (int e = 0; e < NEXP; e++) acc[e] += xv * w[e];
  }
#pragma unroll
  for (int e = 0; e < NEXP; e++) {
    float v = acc[e];
#pragma unroll
    for (int o = 32; o > 0; o >>= 1) v += __shfl_down(v, o);
    acc[e] = v;
  }
  if (lane == 0) {
    float vals[NEXP];
#pragma unroll
    for (int e = 0; e < NEXP; e++) vals[e] = acc[e] + br[e] + gum[(long)wv * NEXP + e];
    int i1 = 0; float b1 = vals[0];
#pragma unroll
    for (int e = 1; e < NEXP; e++) if (vals[e] > b1) { b1 = vals[e]; i1 = e; }
    int i2 = -1; float b2 = -3.4e38f;
#pragma unroll
    for (int e = 0; e < NEXP; e++) if (e != i1 && vals[e] > b2) { b2 = vals[e]; i2 = e; }
    choice[wv] = i1 | (i2 << 4);
    atomicAdd(&cnt[i1], 1);
    atomicAdd(&cnt[i2], 1);
  }
}

// ---------------- prefix: 128-aligned segment base per expert --------------
__global__ void prefix_kernel(const int* __restrict__ cnt, int* __restrict__ base,
                              int* __restrict__ fill) {
  if (threadIdx.x == 0 && blockIdx.x == 0) {
    int off = 0;
    for (int e = 0; e < NEXP; e++) {
      base[e] = off;
      off += (cnt[e] + 127) & ~127;
      fill[e] = 0;
    }
  }
}

// -------- scatter token ids into per-expert lists; record inverse pos ------
__global__ __launch_bounds__(256) void scatter_kernel(
    const int* __restrict__ choice, const int* __restrict__ base,
    int* __restrict__ fill, int* __restrict__ idx, int* __restrict__ pos) {
  int t = blockIdx.x * 256 + threadIdx.x;
  if (t >= T_TOK) return;
  int c = choice[t];
  int e1 = c & 15, e2 = (c >> 4) & 15;
  int p1 = base[e1] + atomicAdd(&fill[e1], 1);
  idx[p1] = t; pos[2 * t] = p1;
  int p2 = base[e2] + atomicAdd(&fill[e2], 1);
  idx[p2] = t; pos[2 * t + 1] = p2;
}

// ---------------- cast x fp32 -> bf16 --------------------------------------
__global__ __launch_bounds__(256) void cast_x_kernel(
    const float* __restrict__ in, ushort_t* __restrict__ out, int n4) {
  int i = blockIdx.x * 256 + threadIdx.x;
  if (i >= n4) return;
  float4 v = ((const float4*)in)[i];
  ushort4 o = make_ushort4(f2bf(v.x), f2bf(v.y), f2bf(v.z), f2bf(v.w));
  ((ushort4*)out)[i] = o;
}

// ------- transpose+cast all 10 experts: fp32 [R][C] -> bf16 [C][R] ---------
__global__ __launch_bounds__(256) void transpose_cast10(
    const float* __restrict__ inS, const float* __restrict__ inE,
    ushort_t* __restrict__ out, int R, int C) {
  __shared__ float tile[32][33];
  int z = blockIdx.z;
  const float* in = (z < NSHARED) ? inS + (size_t)z * R * C
                                  : inE + (size_t)(z - NSHARED) * R * C;
  ushort_t* op = out + (size_t)z * R * C;
  int c0 = blockIdx.x * 32, r0 = blockIdx.y * 32;
  int tx = threadIdx.x, ty = threadIdx.y;  // block (32,8)
#pragma unroll
  for (int k = 0; k < 4; k++)
    tile[ty + 8 * k][tx] = in[(long)(r0 + ty + 8 * k) * C + (c0 + tx)];
  __syncthreads();
#pragma unroll
  for (int k = 0; k < 4; k++)
    op[(long)(c0 + ty + 8 * k) * R + (r0 + tx)] = f2bf(tile[tx][ty + 8 * k]);
}

// ============ GEMM1 merged: 256x256 tile, BK=32, 8 waves (2Mx4N) ===========
// LDS chunk-major [k-chunk 0..3][row 0..255][8 elems] per buffer: staging is
// linear (global_load_lds-legal), frag reads spread banks. 3 bufs, 2-ahead
// counted-vmcnt pipeline (round-3-verified skeleton).
__global__ __launch_bounds__(512, 2) void gemm1_kernel(
    const ushort_t* __restrict__ xb, const ushort_t* __restrict__ W1t,
    const float* __restrict__ bs1, const float* __restrict__ be1,
    ushort_t* __restrict__ h_sh, ushort_t* __restrict__ h_rt,
    const int* __restrict__ cnt, const int* __restrict__ base,
    const int* __restrict__ idx) {
  __shared__ ushort_t As[3][8192];   // 16KB per buf
  __shared__ ushort_t Bs[3][8192];

  int tid = threadIdx.x;             // 0..511
  int z = blockIdx.z;
  int l = blockIdx.x + gridDim.x * blockIdx.y;   // grid 16x16
  int bx = (l & 7) + ((l >> 7) << 3);
  int by = (l >> 3) & 15;
  int row0 = by * 256, col0 = bx * 256;
  bool shd = (z < NSHARED);

  int e = 0, M = T_TOK, base_e = 0;
  const ushort_t* Bp;
  const float* bias;
  if (shd) {
    Bp = W1t + (size_t)z * HDIM * DDIM;
    bias = bs1 + (size_t)z * HDIM;
  } else {
    e = z - NSHARED; M = cnt[e];
    if (row0 >= M) return;            // block-uniform exit, before any barrier
    base_e = base[e];
    Bp = W1t + (size_t)(NSHARED + e) * HDIM * DDIM;
    bias = be1 + (size_t)e * HDIM;
  }

  // staging: thread handles row=tid&255, chunks (tid>>8) and (tid>>8)+2
  int srow = tid & 255, sch = tid >> 8;
  const ushort_t* aP;
  if (shd) {
    aP = xb + (size_t)(row0 + srow) * DDIM + sch * 8;
  } else {
    int s1 = row0 + srow; if (s1 > M - 1) s1 = M - 1;
    aP = xb + (size_t)idx[base_e + s1] * DDIM + sch * 8;
  }
  const ushort_t* bP = Bp + (size_t)(col0 + srow) * DDIM + sch * 8;

  int lane = tid & 63, wv = tid >> 6;   // 8 waves
  int wr = wv >> 2, wc = wv & 3;        // 2(M) x 4(N)
  int ln = lane & 15, quad = lane >> 4;
  f32x4 acc[8][4] = {};
  const int rdA = quad * 2048 + (wr * 128 + ln) * 8;   // + f*128
  const int rdB = quad * 2048 + (wc * 64 + ln) * 8;    // + g*128

#define G1_STAGE(t, c) { size_t kk = (size_t)(t) * 32;            \
    async_copy16(aP + kk,      As[c] + tid * 8);                  \
    async_copy16(aP + kk + 16, As[c] + tid * 8 + 4096);           \
    async_copy16(bP + kk,      Bs[c] + tid * 8);                  \
    async_copy16(bP + kk + 16, Bs[c] + tid * 8 + 4096); }

#define G1_COMPUTE(c) {                                           \
    const ushort_t* aB_ = As[c] + rdA;                            \
    const ushort_t* bB_ = Bs[c] + rdB;                            \
    short8 bfr[4];                                                \
    _Pragma("unroll") for (int g = 0; g < 4; g++)                 \
      bfr[g] = *(const short8*)(bB_ + g * 128);                   \
    _Pragma("unroll") for (int f = 0; f < 8; f++) {               \
      short8 afr = *(const short8*)(aB_ + f * 128);               \
      __builtin_amdgcn_s_setprio(1);                              \
      _Pragma("unroll") for (int g = 0; g < 4; g++)               \
        acc[f][g] = __builtin_amdgcn_mfma_f32_16x16x32_bf16(      \
            afr, bfr[g], acc[f][g], 0, 0, 0);                     \
      __builtin_amdgcn_s_setprio(0);                              \
    } }

  const int NT = DDIM / 32;           // 32 K-tiles
  G1_STAGE(0, 0);
  G1_STAGE(1, 1);
  PIPE_BOUNDARY();

  int c0 = 0, c1 = 1, c2 = 2;
  for (int t = 0; t < NT - 2; ++t) {
    G1_STAGE(t + 2, c2);
    G1_COMPUTE(c0);
    PIPE_BOUNDARY();
    int tmp = c0; c0 = c1; c1 = c2; c2 = tmp;
  }
  G1_COMPUTE(c0);
  __syncthreads();                    // full drain — tail only
  G1_COMPUTE(c1);

  // epilogue: C/D layout col=lane&15, row=quad*4+reg
#pragma unroll
  for (int f = 0; f < 8; f++) {
    int rowB = row0 + wr * 128 + f * 16 + quad * 4;
#pragma unroll
    for (int g = 0; g < 4; g++) {
      int col = col0 + wc * 64 + g * 16 + ln;
      float b = bias[col];
#pragma unroll
      for (int r = 0; r < 4; r++) {
        int t = rowB + r;
        float v = gelu_tanh(acc[f][g][r] + b);
        if (shd) {
          h_sh[(size_t)t * (2 * HDIM) + (size_t)z * HDIM + col] = f2bf(v);
        } else if (t < M) {
          h_rt[((size_t)base_e + t) * HDIM + col] = f2bf(v);
        }
      }
    }
  }
#undef G1_STAGE
#undef G1_COMPUTE
}

// ============ GEMM2: 256x256 tile (N=1024 -> 4 col tiles), K=4096 ==========
__global__ __launch_bounds__(512, 2) void gemm2_kernel(
    const ushort_t* __restrict__ h_sh, const ushort_t* __restrict__ h_rt,
    const ushort_t* __restrict__ W2t, float* __restrict__ outShA,
    float* __restrict__ outShB, float* __restrict__ outRt,
    const int* __restrict__ cnt, const int* __restrict__ base) {
  __shared__ ushort_t As[3][8192];
  __shared__ ushort_t Bs[3][8192];

  int tid = threadIdx.x;
  int z = blockIdx.z;
  int l = blockIdx.x + gridDim.x * blockIdx.y;   // grid 4x16
  int bx = l & 3;
  int by = (l >> 2) & 15;
  int row0 = by * 256, col0 = bx * 256;
  bool shd = (z < NSHARED);

  int e = 0, M = T_TOK, base_e = 0;
  const ushort_t* Ap;
  long lda;
  const ushort_t* Bp;
  float* outP;
  if (shd) {
    Ap = h_sh + (size_t)z * HDIM;   // column offset within row stride 2H
    lda = 2 * HDIM;
    Bp = W2t + (size_t)z * DDIM * HDIM;
    outP = (z == 0) ? outShA : outShB;
  } else {
    e = z - NSHARED; M = cnt[e];
    if (row0 >= M) return;
    base_e = base[e];
    Ap = h_rt + (size_t)base_e * HDIM;
    lda = HDIM;
    Bp = W2t + (size_t)(NSHARED + e) * DDIM * HDIM;
    outP = outRt + (size_t)base_e * DDIM;
  }

  int srow = tid & 255, sch = tid >> 8;
  int s1 = row0 + srow;
  if (!shd && s1 > M - 1) s1 = M - 1;
  const ushort_t* aP = Ap + (long)s1 * lda + sch * 8;
  const ushort_t* bP = Bp + (size_t)(col0 + srow) * HDIM + sch * 8;

  int lane = tid & 63, wv = tid >> 6;
  int wr = wv >> 2, wc = wv & 3;
  int ln = lane & 15, quad = lane >> 4;
  f32x4 acc[8][4] = {};
  const int rdA = quad * 2048 + (wr * 128 + ln) * 8;
  const int rdB = quad * 2048 + (wc * 64 + ln) * 8;

#define G2_STAGE(t, c) { size_t kk = (size_t)(t) * 32;            \
    async_copy16(aP + kk,      As[c] + tid * 8);                  \
    async_copy16(aP + kk + 16, As[c] + tid * 8 + 4096);           \
    async_copy16(bP + kk,      Bs[c] + tid * 8);                  \
    async_copy16(bP + kk + 16, Bs[c] + tid * 8 + 4096); }

#define G2_COMPUTE(c) {                                           \
    const ushort_t* aB_ = As[c] + rdA;                            \
    const ushort_t* bB_ = Bs[c] + rdB;                            \
    short8 bfr[4];                                                \
    _Pragma("unroll") for (int g = 0; g < 4; g++)                 \
      bfr[g] = *(const short8*)(bB_ + g * 128);                   \
    _Pragma("unroll") for (int f = 0; f < 8; f++) {               \
      short8 afr = *(const short8*)(aB_ + f * 128);               \
      __builtin_amdgcn_s_setprio(1);                              \
      _Pragma("unroll") for (int g = 0; g < 4; g++)               \
        acc[f][g] = __builtin_amdgcn_mfma_f32_16x16x32_bf16(      \
            afr, bfr[g], acc[f][g], 0, 0, 0);                     \
      __builtin_amdgcn_s_setprio(0);                              \
    } }

  const int NT = HDIM / 32;           // 128 K-tiles
  G2_STAGE(0, 0);
  G2_STAGE(1, 1);
  PIPE_BOUNDARY();

  int c0 = 0, c1 = 1, c2 = 2;
  for (int t = 0; t < NT - 2; ++t) {
    G2_STAGE(t + 2, c2);
    G2_COMPUTE(c0);
    PIPE_BOUNDARY();
    int tmp = c0; c0 = c1; c1 = c2; c2 = tmp;
  }
  G2_COMPUTE(c0);
  __syncthreads();
  G2_COMPUTE(c1);

#pragma unroll
  for (int f = 0; f < 8; f++) {
    int rowB = row0 + wr * 128 + f * 16 + quad * 4;
#pragma unroll
    for (int g = 0; g < 4; g++) {
      int col = col0 + wc * 64 + g * 16 + ln;
#pragma unroll
      for (int r = 0; r < 4; r++) {
        int t = rowB + r;
        if (shd || t < M) outP[(size_t)t * DDIM + col] = acc[f][g][r];
      }
    }
  }
#undef G2_STAGE
#undef G2_COMPUTE
}

// ---- combine: out = shA + shB + rt[p1] + rt[p2] + (bs2 sum + be2[e1]+be2[e2])
__global__ __launch_bounds__(256) void combine_kernel(
    const float* __restrict__ shA, const float* __restrict__ shB,
    const float* __restrict__ rt, const float* __restrict__ bs2,
    const float* __restrict__ be2, const int* __restrict__ choice,
    const int* __restrict__ pos, float* __restrict__ out) {
  int i = blockIdx.x * 256 + threadIdx.x;     // over T*D/4
  int t = i >> 8;                             // D/4 = 256
  int d4 = i & 255;
  int c = choice[t];
  int e1 = c & 15, e2 = (c >> 4) & 15;
  long p1 = (long)pos[2 * t] * 256 + d4;
  long p2 = (long)pos[2 * t + 1] * 256 + d4;
  float4 a = ((const float4*)shA)[i];
  float4 b = ((const float4*)shB)[i];
  float4 r1 = ((const float4*)rt)[p1];
  float4 r2 = ((const float4*)rt)[p2];
  float4 b0 = ((const float4*)bs2)[d4];
  float4 b1 = ((const float4*)bs2)[256 + d4];
  float4 c1 = ((const float4*)be2)[e1 * 256 + d4];
  float4 c2 = ((const float4*)be2)[e2 * 256 + d4];
  float4 o;
  o.x = a.x + b.x + r1.x + r2.x + b0.x + b1.x + c1.x + c2.x;
  o.y = a.y + b.y + r1.y + r2.y + b0.y + b1.y + c1.y + c2.y;
  o.z = a.z + b.z + r1.z + r2.z + b0.z + b1.z + c1.z + c2.z;
  o.w = a.w + b.w + r1.w + r2.w + b0.w + b1.w + c1.w + c2.w;
  ((float4*)out)[i] = o;
}

extern "C" void kernel_launch(void* const* d_in, const int* in_sizes, int n_in,
                              void* d_out, int out_size, void* d_ws,
                              size_t ws_size, hipStream_t stream) {
  const float* x   = (const float*)d_in[0];
  const float* Ws1 = (const float*)d_in[1];
  const float* bs1 = (const float*)d_in[2];
  const float* Ws2 = (const float*)d_in[3];
  const float* bs2 = (const float*)d_in[4];
  const float* We1 = (const float*)d_in[5];
  const float* be1 = (const float*)d_in[6];
  const float* We2 = (const float*)d_in[7];
  const float* be2 = (const float*)d_in[8];
  const float* Wr  = (const float*)d_in[9];
  const float* br  = (const float*)d_in[10];
  const float* gum = (const float*)d_in[11];
  float* out = (float*)d_out;

  // ---- workspace layout (~308 MB) ----
  char* ws = (char*)d_ws;
  size_t off = 0;
  int* cnt    = (int*)(ws + off); off += 256;
  int* base   = (int*)(ws + off); off += 256;
  int* fill   = (int*)(ws + off); off += 256;
  int* choice = (int*)(ws + off); off += T_TOK * 4;
  int* idx    = (int*)(ws + off); off += RT_CAP * 4;
  int* pos    = (int*)(ws + off); off += T_TOK * 8;
  off = (off + 255) & ~(size_t)255;
  ushort_t* xb   = (ushort_t*)(ws + off); off += (size_t)T_TOK * DDIM * 2;       // 8 MB
  ushort_t* W1t  = (ushort_t*)(ws + off); off += (size_t)10 * HDIM * DDIM * 2;   // 80 MB
  ushort_t* W2t  = (ushort_t*)(ws + off); off += (size_t)10 * DDIM * HDIM * 2;   // 80 MB
  ushort_t* h_sh = (ushort_t*)(ws + off); off += (size_t)T_TOK * 2 * HDIM * 2;   // 64 MB
  ushort_t* h_rt = (ushort_t*)(ws + off); off += (size_t)RT_CAP * HDIM * 2;      // 75.5 MB
  // out buffers ALIAS W1t (dead after gemm1; rewritten by transposes each launch)
  float* outShA = (float*)W1t;                         // 16.8 MB
  float* outShB = outShA + (size_t)T_TOK * DDIM;       // 16.8 MB
  float* outRt  = outShB + (size_t)T_TOK * DDIM;       // 37.7 MB (71.3 <= 80)
  (void)ws_size;

  hipMemsetAsync(cnt, 0, 256, stream);
  router_kernel<<<T_TOK / 4, 256, 0, stream>>>(x, Wr, br, gum, choice, cnt);
  prefix_kernel<<<1, 64, 0, stream>>>(cnt, base, fill);
  scatter_kernel<<<T_TOK / 256, 256, 0, stream>>>(choice, base, fill, idx, pos);
  cast_x_kernel<<<(T_TOK * DDIM / 4 + 255) / 256, 256, 0, stream>>>(
      x, xb, T_TOK * DDIM / 4);

  // W1: [D][H] -> bf16 [H][D] (10 experts, one dispatch); W2 likewise
  transpose_cast10<<<dim3(HDIM / 32, DDIM / 32, 10), dim3(32, 8), 0, stream>>>(
      Ws1, We1, W1t, DDIM, HDIM);
  transpose_cast10<<<dim3(DDIM / 32, HDIM / 32, 10), dim3(32, 8), 0, stream>>>(
      Ws2, We2, W2t, HDIM, DDIM);

  // merged GEMM1: all 10 expert-passes (K=1024), 256x256 tiles
  gemm1_kernel<<<dim3(16, 16, NSHARED + NEXP), 512, 0, stream>>>(
      xb, W1t, bs1, be1, h_sh, h_rt, cnt, base, idx);
  // GEMM2: z=0/1 shared experts -> outShA/B; z>=2 routing -> outRt (K=4096)
  gemm2_kernel<<<dim3(4, 16, NSHARED + NEXP), 512, 0, stream>>>(
      h_sh, h_rt, W2t, outShA, outShB, outRt, cnt, base);
  // final gather-add (+ all output biases)
  combine_kernel<<<T_TOK * DDIM / 4 / 256, 256, 0, stream>>>(
      outShA, outShB, outRt, bs2, be2, choice, pos, out);

  (void)in_sizes; (void)n_in; (void)out_size;
}